// Round 1
// baseline (823.455 us; speedup 1.0000x reference)
//
#include <hip/hip_runtime.h>
#include <hip/hip_bf16.h>

#define N_GRAPHS 64

// ---------------------------------------------------------------------------
// deg count: deg[dst[e]] += 1
__global__ void k_deg(const int* __restrict__ dst, int E, int* __restrict__ deg) {
    int i = blockIdx.x * blockDim.x + threadIdx.x;
    if (i < E) atomicAdd(&deg[dst[i]], 1);
}

// dis[i] = rsqrt(deg+1) ; xp[i] = dis[i]*x[i]
__global__ void k_dis(const int* __restrict__ deg, const float* __restrict__ x,
                      float* __restrict__ dis, float* __restrict__ xp, int N) {
    int i = blockIdx.x * blockDim.x + threadIdx.x;
    if (i < N) {
        float d = rsqrtf((float)(deg[i] + 1));   // self-loop included
        dis[i] = d;
        xp[i]  = d * x[i];
    }
}

// single-block exclusive scan -> row_ptr[0..N]
__global__ void k_scan(const int* __restrict__ deg, int* __restrict__ row_ptr, int N) {
    __shared__ int lds[1024];
    __shared__ int carry;
    const int tid = threadIdx.x;
    if (tid == 0) { carry = 0; row_ptr[0] = 0; }
    __syncthreads();
    for (int base = 0; base < N; base += 1024) {
        int i = base + tid;
        int v = (i < N) ? deg[i] : 0;
        lds[tid] = v;
        __syncthreads();
        for (int off = 1; off < 1024; off <<= 1) {
            int add = (tid >= off) ? lds[tid - off] : 0;
            __syncthreads();
            lds[tid] += add;
            __syncthreads();
        }
        int inc = lds[tid] + carry;
        if (i < N) row_ptr[i + 1] = inc;
        __syncthreads();
        if (tid == 1023) carry = inc;
        __syncthreads();
    }
}

// scatter edges into CSR (indexed by dst, storing src)
__global__ void k_scatter(const int* __restrict__ src, const int* __restrict__ dst, int E,
                          const int* __restrict__ row_ptr, int* __restrict__ fill,
                          int* __restrict__ csr_src) {
    int e = blockIdx.x * blockDim.x + threadIdx.x;
    if (e < E) {
        int d = dst[e];
        int pos = row_ptr[d] + atomicAdd(&fill[d], 1);
        csr_src[pos] = src[e];
    }
}

// t[d] = dis[d] * ( sum_{s in N(d)} xp[s] + xp[d] )   (scalar layer-1 aggregation)
__global__ void k_agg_scalar(const float* __restrict__ xp, const float* __restrict__ dis,
                             const int* __restrict__ row_ptr, const int* __restrict__ csr,
                             float* __restrict__ t, int N) {
    int d = blockIdx.x * blockDim.x + threadIdx.x;
    if (d >= N) return;
    float acc = xp[d];
    int e0 = row_ptr[d], e1 = row_ptr[d + 1];
    for (int e = e0; e < e1; ++e) acc += xp[csr[e]];
    t[d] = dis[d] * acc;
}

// h1'[i][j] = dis[i] * relu(t[i]*W1[j] + b1[j])
__global__ void k_h1(const float* __restrict__ t, const float* __restrict__ dis,
                     const float* __restrict__ W1, const float* __restrict__ b1,
                     float* __restrict__ h1, int N) {
    __shared__ float w[128], bb[128];
    const int tid = threadIdx.x;
    if (tid < 128) { w[tid] = W1[tid]; bb[tid] = b1[tid]; }
    __syncthreads();
    int idx = blockIdx.x * 256 + tid;
    if (idx < N * 128) {
        int i = idx >> 7, j = idx & 127;
        float v = fmaf(t[i], w[j], bb[j]);
        h1[idx] = fmaxf(v, 0.f) * dis[i];
    }
}

// out[d][j] = dis[d] * ( sum_{s in N(d)} hp[s][j] + hp[d][j] ),  F = 128
// 2 nodes per 256-thread block, one thread per feature.
__global__ void k_agg128(const float* __restrict__ hp, const float* __restrict__ dis,
                         const int* __restrict__ row_ptr, const int* __restrict__ csr,
                         float* __restrict__ out, int N) {
    int node = blockIdx.x * 2 + (threadIdx.x >> 7);
    int j = threadIdx.x & 127;
    if (node >= N) return;
    float acc = hp[(size_t)node * 128 + j];
    int e0 = row_ptr[node], e1 = row_ptr[node + 1];
    for (int e = e0; e < e1; ++e) {
        int s = csr[e];
        acc += hp[(size_t)s * 128 + j];
    }
    out[(size_t)node * 128 + j] = dis[node] * acc;
}

// out[i][jh*128+j] = (relu( A[i,:] @ W[:, jh*128+j] + b ))  (* dis[i] if SCALE)
// K = 128 fixed. 32 nodes per block, W half (128x128) + A tile in LDS.
template<int FOUT, bool SCALE>
__global__ __launch_bounds__(256) void k_gemm(const float* __restrict__ A,
                                              const float* __restrict__ W,
                                              const float* __restrict__ b,
                                              const float* __restrict__ dis,
                                              float* __restrict__ out, int N) {
    __shared__ float Alds[32 * 128];    // 16 KiB
    __shared__ float Wlds[128 * 128];   // 64 KiB
    const int tid = threadIdx.x;
    const int n0 = blockIdx.x * 32;
    const int jh = blockIdx.y;

    {   // stage A tile (guard partial last tile)
        const float4* Ag = reinterpret_cast<const float4*>(A + (size_t)n0 * 128);
        float4* Al = reinterpret_cast<float4*>(Alds);
        int f4valid = (min(32, N - n0)) * 32;
        for (int q = tid; q < 32 * 32; q += 256)
            Al[q] = (q < f4valid) ? Ag[q] : make_float4(0.f, 0.f, 0.f, 0.f);
    }
    {   // stage W column-half: Wlds[k][j] = W[k*FOUT + jh*128 + j]
        for (int q = tid; q < 128 * 32; q += 256) {
            int k = q >> 5, jc = q & 31;
            const float4* Wg = reinterpret_cast<const float4*>(W + (size_t)k * FOUT + jh * 128);
            reinterpret_cast<float4*>(&Wlds[k * 128])[jc] = Wg[jc];
        }
    }
    __syncthreads();

    const int n  = tid >> 3;
    const int j0 = (tid & 7) * 16;
    float acc[16];
#pragma unroll
    for (int jj = 0; jj < 16; ++jj) acc[jj] = 0.f;
#pragma unroll 4
    for (int k = 0; k < 128; ++k) {
        float a = Alds[n * 128 + k];
#pragma unroll
        for (int jj = 0; jj < 16; ++jj)
            acc[jj] = fmaf(a, Wlds[k * 128 + j0 + jj], acc[jj]);
    }
    int node = n0 + n;
    if (node < N) {
        float dsc = SCALE ? dis[node] : 1.f;
#pragma unroll
        for (int jj = 0; jj < 16; ++jj) {
            float v = acc[jj] + b[jh * 128 + j0 + jj];
            v = fmaxf(v, 0.f);
            out[(size_t)node * FOUT + jh * 128 + j0 + jj] = SCALE ? v * dsc : v;
        }
    }
}

// graph boundary offsets from sorted batch
__global__ void k_bounds(const int* __restrict__ batch, int N, int* __restrict__ gstart) {
    int i = blockIdx.x * blockDim.x + threadIdx.x;
    if (i >= N) return;
    int b = batch[i];
    int prev = (i == 0) ? -1 : batch[i - 1];
    for (int g = prev + 1; g <= b; ++g) gstart[g] = i;
    if (i == N - 1) for (int g = b + 1; g <= N_GRAPHS; ++g) gstart[g] = N;
}

// per-graph max over h3 (values >= 0 post-relu, so identity 0 is safe)
__global__ void k_gmax(const float* __restrict__ h3, const int* __restrict__ gstart,
                       float* __restrict__ g) {
    int gid = blockIdx.x;
    int f = blockIdx.y * 128 + threadIdx.x;
    int r0 = gstart[gid], r1 = gstart[gid + 1];
    float m = 0.f;
    for (int i = r0; i < r1; ++i)
        m = fmaxf(m, h3[(size_t)i * 256 + f]);
    g[gid * 256 + f] = m;
}

// final MLP: out = relu( relu(g@Wf1+bf1) @ Wf2 + bf2 )
__global__ void k_mlp(const float* __restrict__ g, const float* __restrict__ Wf1,
                      const float* __restrict__ bf1, const float* __restrict__ Wf2,
                      const float* __restrict__ bf2, float* __restrict__ out) {
    __shared__ float gr[256];
    __shared__ float g1s[128];
    const int gid = blockIdx.x;
    const int tid = threadIdx.x;
    gr[tid] = g[gid * 256 + tid];
    gr[tid + 128] = g[gid * 256 + 128 + tid];
    __syncthreads();
    float acc = bf1[tid];
    for (int k = 0; k < 256; ++k)
        acc = fmaf(gr[k], Wf1[k * 128 + tid], acc);
    g1s[tid] = fmaxf(acc, 0.f);
    __syncthreads();
    if (tid < 10) {
        float a = bf2[tid];
        for (int k = 0; k < 128; ++k)
            a = fmaf(g1s[k], Wf2[k * 10 + tid], a);
        out[gid * 10 + tid] = fmaxf(a, 0.f);
    }
}

// ---------------------------------------------------------------------------
extern "C" void kernel_launch(void* const* d_in, const int* in_sizes, int n_in,
                              void* d_out, int out_size, void* d_ws, size_t ws_size,
                              hipStream_t stream) {
    const float* x   = (const float*)d_in[0];
    const int*   ei  = (const int*)d_in[1];
    const int*   bat = (const int*)d_in[2];
    const float* W1  = (const float*)d_in[3];
    const float* b1  = (const float*)d_in[4];
    const float* W2  = (const float*)d_in[5];
    const float* b2  = (const float*)d_in[6];
    const float* W3  = (const float*)d_in[7];
    const float* b3  = (const float*)d_in[8];
    const float* Wf1 = (const float*)d_in[9];
    const float* bf1 = (const float*)d_in[10];
    const float* Wf2 = (const float*)d_in[11];
    const float* bf2 = (const float*)d_in[12];
    float* out = (float*)d_out;

    const int N = in_sizes[0];          // 50000
    const int E = in_sizes[1] / 2;      // 800000
    const int* src = ei;
    const int* dst = ei + E;

    // workspace carve-up (256B aligned)
    char* base = (char*)d_ws;
    size_t off = 0;
    auto carve = [&](size_t bytes) -> char* {
        char* p = base + off;
        off = (off + bytes + 255) & ~(size_t)255;
        return p;
    };
    int*   deg     = (int*)  carve((size_t)N * 4);
    int*   fill    = (int*)  carve((size_t)N * 4);
    int*   row_ptr = (int*)  carve((size_t)(N + 1) * 4);
    int*   csr     = (int*)  carve((size_t)E * 4);
    float* dis     = (float*)carve((size_t)N * 4);
    float* xp      = (float*)carve((size_t)N * 4);
    float* t       = (float*)carve((size_t)N * 4);
    float* B1      = (float*)carve((size_t)N * 128 * 4);
    float* B2      = (float*)carve((size_t)N * 128 * 4);
    float* B3      = (float*)carve((size_t)N * 256 * 4);
    int*   gstart  = (int*)  carve((size_t)(N_GRAPHS + 1) * 4);
    float* g       = (float*)carve((size_t)N_GRAPHS * 256 * 4);
    (void)ws_size; (void)n_in; (void)out_size;

    hipMemsetAsync(deg, 0, (size_t)N * 4, stream);
    hipMemsetAsync(fill, 0, (size_t)N * 4, stream);

    int eb = (E + 255) / 256;
    int nb = (N + 255) / 256;

    k_deg<<<eb, 256, 0, stream>>>(dst, E, deg);
    k_dis<<<nb, 256, 0, stream>>>(deg, x, dis, xp, N);
    k_scan<<<1, 1024, 0, stream>>>(deg, row_ptr, N);
    k_scatter<<<eb, 256, 0, stream>>>(src, dst, E, row_ptr, fill, csr);

    k_agg_scalar<<<nb, 256, 0, stream>>>(xp, dis, row_ptr, csr, t, N);
    k_h1<<<(N * 128 + 255) / 256, 256, 0, stream>>>(t, dis, W1, b1, B1, N);

    k_agg128<<<(N + 1) / 2, 256, 0, stream>>>(B1, dis, row_ptr, csr, B2, N);
    k_gemm<128, true><<<dim3((N + 31) / 32, 1), 256, 0, stream>>>(B2, W2, b2, dis, B1, N);

    k_agg128<<<(N + 1) / 2, 256, 0, stream>>>(B1, dis, row_ptr, csr, B2, N);
    k_gemm<256, false><<<dim3((N + 31) / 32, 2), 256, 0, stream>>>(B2, W3, b3, nullptr, B3, N);

    k_bounds<<<nb, 256, 0, stream>>>(bat, N, gstart);
    k_gmax<<<dim3(N_GRAPHS, 2), 128, 0, stream>>>(B3, gstart, g);
    k_mlp<<<N_GRAPHS, 128, 0, stream>>>(g, Wf1, bf1, Wf2, bf2, out);
}

// Round 2
// 413.924 us; speedup vs baseline: 1.9894x; 1.9894x over previous
//
#include <hip/hip_runtime.h>
#include <hip/hip_bf16.h>

#define N_GRAPHS 64

// ---------------------------------------------------------------------------
__global__ void k_deg(const int* __restrict__ dst, int E, int* __restrict__ deg) {
    int i = blockIdx.x * blockDim.x + threadIdx.x;
    if (i < E) atomicAdd(&deg[dst[i]], 1);
}

__global__ void k_dis(const int* __restrict__ deg, const float* __restrict__ x,
                      float* __restrict__ dis, float* __restrict__ xp, int N) {
    int i = blockIdx.x * blockDim.x + threadIdx.x;
    if (i < N) {
        float d = rsqrtf((float)(deg[i] + 1));
        dis[i] = d;
        xp[i]  = d * x[i];
    }
}

// ---- hierarchical exclusive scan of deg -> row_ptr[0..N] -------------------
__device__ inline int block_scan_inc(int v, int* wsum) {
    int lane = threadIdx.x & 63, w = threadIdx.x >> 6;
    int iv = v;
#pragma unroll
    for (int o = 1; o < 64; o <<= 1) {
        int t = __shfl_up(iv, o);
        if (lane >= o) iv += t;
    }
    if (lane == 63) wsum[w] = iv;
    __syncthreads();
    int add = 0;
    for (int k = 0; k < w; ++k) add += wsum[k];
    return iv + add;
}

__global__ void k_bsum(const int* __restrict__ deg, int N, int* __restrict__ bsum) {
    int i = blockIdx.x * 256 + threadIdx.x;
    int v = (i < N) ? deg[i] : 0;
#pragma unroll
    for (int o = 1; o < 64; o <<= 1) v += __shfl_xor(v, o);
    __shared__ int ws4[4];
    if ((threadIdx.x & 63) == 0) ws4[threadIdx.x >> 6] = v;
    __syncthreads();
    if (threadIdx.x == 0) bsum[blockIdx.x] = ws4[0] + ws4[1] + ws4[2] + ws4[3];
}

__global__ void k_scan_sums(const int* __restrict__ bsum, int nb, int* __restrict__ boff) {
    __shared__ int wsum[4];
    int tid = threadIdx.x;
    int v = (tid < nb) ? bsum[tid] : 0;
    int inc = block_scan_inc(v, wsum);
    if (tid < nb) boff[tid] = inc - v;   // exclusive
}

__global__ void k_scan_apply(const int* __restrict__ deg, const int* __restrict__ boff,
                             int* __restrict__ row_ptr, int N) {
    __shared__ int wsum[4];
    int b = blockIdx.x, i = b * 256 + threadIdx.x;
    int v = (i < N) ? deg[i] : 0;
    int inc = block_scan_inc(v, wsum) + boff[b];
    if (i < N) {
        row_ptr[i] = inc - v;
        if (i == N - 1) row_ptr[N] = inc;
    }
}

// ---------------------------------------------------------------------------
__global__ void k_scatter(const int* __restrict__ src, const int* __restrict__ dst, int E,
                          const int* __restrict__ row_ptr, int* __restrict__ fill,
                          int* __restrict__ csr_src) {
    int e = blockIdx.x * blockDim.x + threadIdx.x;
    if (e < E) {
        int d = dst[e];
        int pos = row_ptr[d] + atomicAdd(&fill[d], 1);
        csr_src[pos] = src[e];
    }
}

// t[d] = dis[d] * ( sum xp[s] + xp[d] )
__global__ void k_agg_scalar(const float* __restrict__ xp, const float* __restrict__ dis,
                             const int* __restrict__ row_ptr, const int* __restrict__ csr,
                             float* __restrict__ t, int N) {
    int d = blockIdx.x * blockDim.x + threadIdx.x;
    if (d >= N) return;
    float acc = xp[d];
    int e0 = row_ptr[d], e1 = row_ptr[d + 1];
    int e = e0;
    for (; e + 4 <= e1; e += 4) {
        int s0 = csr[e], s1 = csr[e + 1], s2 = csr[e + 2], s3 = csr[e + 3];
        acc += xp[s0] + xp[s1] + xp[s2] + xp[s3];
    }
    for (; e < e1; ++e) acc += xp[csr[e]];
    t[d] = dis[d] * acc;
}

// h1'[i][j] = dis[i] * relu(t[i]*W1[j] + b1[j])
__global__ void k_h1(const float* __restrict__ t, const float* __restrict__ dis,
                     const float* __restrict__ W1, const float* __restrict__ b1,
                     float* __restrict__ h1, int N) {
    __shared__ float w[128], bb[128];
    const int tid = threadIdx.x;
    if (tid < 128) { w[tid] = W1[tid]; bb[tid] = b1[tid]; }
    __syncthreads();
    int idx = blockIdx.x * 256 + tid;
    if (idx < N * 128) {
        int i = idx >> 7, j = idx & 127;
        float v = fmaf(t[i], w[j], bb[j]);
        h1[idx] = fmaxf(v, 0.f) * dis[i];
    }
}

// out[d][:] = dis[d] * ( sum_{s in N(d)} hp[s][:] + hp[d][:] ),  F = 128
// float4 per lane, 32 lanes per node, 8 nodes per 256-thread block.
// 4-edge unroll keeps 4 independent 1KB wave-loads in flight.
__global__ void k_agg128(const float4* __restrict__ hp4, const float* __restrict__ dis,
                         const int* __restrict__ row_ptr, const int* __restrict__ csr,
                         float4* __restrict__ out4, int N) {
    int node = blockIdx.x * 8 + (threadIdx.x >> 5);
    int lane = threadIdx.x & 31;
    if (node >= N) return;
    float4 self = hp4[(size_t)node * 32 + lane];
    float a0 = self.x, a1 = self.y, a2 = self.z, a3 = self.w;
    int e0 = row_ptr[node], e1 = row_ptr[node + 1];
    int e = e0;
    for (; e + 4 <= e1; e += 4) {
        int s0 = csr[e], s1 = csr[e + 1], s2 = csr[e + 2], s3 = csr[e + 3];
        float4 v0 = hp4[(size_t)s0 * 32 + lane];
        float4 v1 = hp4[(size_t)s1 * 32 + lane];
        float4 v2 = hp4[(size_t)s2 * 32 + lane];
        float4 v3 = hp4[(size_t)s3 * 32 + lane];
        a0 += (v0.x + v1.x) + (v2.x + v3.x);
        a1 += (v0.y + v1.y) + (v2.y + v3.y);
        a2 += (v0.z + v1.z) + (v2.z + v3.z);
        a3 += (v0.w + v1.w) + (v2.w + v3.w);
    }
    for (; e < e1; ++e) {
        int s = csr[e];
        float4 v = hp4[(size_t)s * 32 + lane];
        a0 += v.x; a1 += v.y; a2 += v.z; a3 += v.w;
    }
    float d = dis[node];
    out4[(size_t)node * 32 + lane] = make_float4(a0 * d, a1 * d, a2 * d, a3 * d);
}

// GEMM: out[n][jh*128+j] = relu( A[n,:] @ W[:, jh*128+j] + b ) (* dis[n] if SCALE)
// K=128. Block tile 64 nodes x 128 cols; thread tile 4 nodes x 8 cols.
// A staged transposed At[k][n] (conflict-free), W staged Wl[k][j].
template<int FOUT, bool SCALE>
__global__ __launch_bounds__(256) void k_gemm(const float* __restrict__ A,
                                              const float* __restrict__ W,
                                              const float* __restrict__ b,
                                              const float* __restrict__ dis,
                                              float* __restrict__ out, int N) {
    __shared__ float At[128][64];    // 32 KiB, At[k][n]
    __shared__ float Wl[128][128];   // 64 KiB, Wl[k][j]
    const int tid = threadIdx.x;
    const int n0 = blockIdx.x * 64;
    const int jh = blockIdx.y;

    // stage W column-slab (coalesced)
    for (int q = tid; q < 128 * 32; q += 256) {
        int k = q >> 5, jc = q & 31;
        reinterpret_cast<float4*>(&Wl[k][0])[jc] =
            reinterpret_cast<const float4*>(W + (size_t)k * FOUT + jh * 128)[jc];
    }
    // stage A transposed: lane-major over nodes -> conflict-free LDS writes
    for (int q = tid; q < 64 * 32; q += 256) {
        int nn = q & 63, kq = q >> 6;   // kq in [0,32)
        int node = n0 + nn;
        float4 a = (node < N)
            ? reinterpret_cast<const float4*>(A + (size_t)node * 128)[kq]
            : make_float4(0.f, 0.f, 0.f, 0.f);
        At[kq * 4 + 0][nn] = a.x;
        At[kq * 4 + 1][nn] = a.y;
        At[kq * 4 + 2][nn] = a.z;
        At[kq * 4 + 3][nn] = a.w;
    }
    __syncthreads();

    const int ng = tid >> 4;   // 0..15 -> nodes ng*4 .. +3
    const int cg = tid & 15;   // 0..15 -> cols  cg*8 .. +7
    float acc[4][8] = {};
#pragma unroll 4
    for (int k = 0; k < 128; ++k) {
        const float4 a  = *reinterpret_cast<const float4*>(&At[k][ng * 4]);
        const float4 w0 = *reinterpret_cast<const float4*>(&Wl[k][cg * 8]);
        const float4 w1 = *reinterpret_cast<const float4*>(&Wl[k][cg * 8 + 4]);
        const float av[4] = {a.x, a.y, a.z, a.w};
        const float wv[8] = {w0.x, w0.y, w0.z, w0.w, w1.x, w1.y, w1.z, w1.w};
#pragma unroll
        for (int i = 0; i < 4; ++i)
#pragma unroll
            for (int j = 0; j < 8; ++j)
                acc[i][j] = fmaf(av[i], wv[j], acc[i][j]);
    }

    const float* bb = b + jh * 128 + cg * 8;
#pragma unroll
    for (int i = 0; i < 4; ++i) {
        int node = n0 + ng * 4 + i;
        if (node < N) {
            float dsc = SCALE ? dis[node] : 1.f;
            float o[8];
#pragma unroll
            for (int j = 0; j < 8; ++j) {
                float v = fmaxf(acc[i][j] + bb[j], 0.f);
                o[j] = SCALE ? v * dsc : v;
            }
            float* op = out + (size_t)node * FOUT + jh * 128 + cg * 8;
            *reinterpret_cast<float4*>(op)     = make_float4(o[0], o[1], o[2], o[3]);
            *reinterpret_cast<float4*>(op + 4) = make_float4(o[4], o[5], o[6], o[7]);
        }
    }
}

// graph boundary offsets from sorted batch
__global__ void k_bounds(const int* __restrict__ batch, int N, int* __restrict__ gstart) {
    int i = blockIdx.x * blockDim.x + threadIdx.x;
    if (i >= N) return;
    int b = batch[i];
    int prev = (i == 0) ? -1 : batch[i - 1];
    for (int g = prev + 1; g <= b; ++g) gstart[g] = i;
    if (i == N - 1) for (int g = b + 1; g <= N_GRAPHS; ++g) gstart[g] = N;
}

// per-graph max: grid (64 graphs x 16 chunks), 64 threads, float4/lane.
// Values are >= 0 post-relu, so uint bit-pattern atomicMax == float max.
__global__ void k_gmax(const float4* __restrict__ h3, const int* __restrict__ gstart,
                       unsigned int* __restrict__ g) {
    int gid = blockIdx.x;
    int c = blockIdx.y;
    int lane = threadIdx.x;
    int r0 = gstart[gid], r1 = gstart[gid + 1];
    int len = r1 - r0;
    int per = (len + 15) >> 4;
    int s = r0 + c * per;
    int e = min(r1, s + per);
    float4 m = make_float4(0.f, 0.f, 0.f, 0.f);
    for (int i = s; i < e; ++i) {
        float4 v = h3[(size_t)i * 64 + lane];
        m.x = fmaxf(m.x, v.x); m.y = fmaxf(m.y, v.y);
        m.z = fmaxf(m.z, v.z); m.w = fmaxf(m.w, v.w);
    }
    unsigned int* gp = g + gid * 256 + lane * 4;
    atomicMax(gp + 0, __float_as_uint(m.x));
    atomicMax(gp + 1, __float_as_uint(m.y));
    atomicMax(gp + 2, __float_as_uint(m.z));
    atomicMax(gp + 3, __float_as_uint(m.w));
}

// final MLP: out = relu( relu(g@Wf1+bf1) @ Wf2 + bf2 )
__global__ void k_mlp(const float* __restrict__ g, const float* __restrict__ Wf1,
                      const float* __restrict__ bf1, const float* __restrict__ Wf2,
                      const float* __restrict__ bf2, float* __restrict__ out) {
    __shared__ float gr[256];
    __shared__ float g1s[128];
    const int gid = blockIdx.x;
    const int tid = threadIdx.x;
    gr[tid] = g[gid * 256 + tid];
    gr[tid + 128] = g[gid * 256 + 128 + tid];
    __syncthreads();
    float acc = bf1[tid];
    for (int k = 0; k < 256; ++k)
        acc = fmaf(gr[k], Wf1[k * 128 + tid], acc);
    g1s[tid] = fmaxf(acc, 0.f);
    __syncthreads();
    if (tid < 10) {
        float a = bf2[tid];
        for (int k = 0; k < 128; ++k)
            a = fmaf(g1s[k], Wf2[k * 10 + tid], a);
        out[gid * 10 + tid] = fmaxf(a, 0.f);
    }
}

// ---------------------------------------------------------------------------
extern "C" void kernel_launch(void* const* d_in, const int* in_sizes, int n_in,
                              void* d_out, int out_size, void* d_ws, size_t ws_size,
                              hipStream_t stream) {
    const float* x   = (const float*)d_in[0];
    const int*   ei  = (const int*)d_in[1];
    const int*   bat = (const int*)d_in[2];
    const float* W1  = (const float*)d_in[3];
    const float* b1  = (const float*)d_in[4];
    const float* W2  = (const float*)d_in[5];
    const float* b2  = (const float*)d_in[6];
    const float* W3  = (const float*)d_in[7];
    const float* b3  = (const float*)d_in[8];
    const float* Wf1 = (const float*)d_in[9];
    const float* bf1 = (const float*)d_in[10];
    const float* Wf2 = (const float*)d_in[11];
    const float* bf2 = (const float*)d_in[12];
    float* out = (float*)d_out;

    const int N = in_sizes[0];          // 50000
    const int E = in_sizes[1] / 2;      // 800000
    const int* src = ei;
    const int* dst = ei + E;

    char* base = (char*)d_ws;
    size_t off = 0;
    auto carve = [&](size_t bytes) -> char* {
        char* p = base + off;
        off = (off + bytes + 255) & ~(size_t)255;
        return p;
    };
    const int nb = (N + 255) / 256;
    int*   deg     = (int*)  carve((size_t)N * 4);
    int*   fill    = (int*)  carve((size_t)N * 4);
    int*   row_ptr = (int*)  carve((size_t)(N + 1) * 4);
    int*   csr     = (int*)  carve((size_t)E * 4);
    float* dis     = (float*)carve((size_t)N * 4);
    float* xp      = (float*)carve((size_t)N * 4);
    float* t       = (float*)carve((size_t)N * 4);
    float* B1      = (float*)carve((size_t)N * 128 * 4);
    float* B2      = (float*)carve((size_t)N * 128 * 4);
    float* B3      = (float*)carve((size_t)N * 256 * 4);
    int*   gstart  = (int*)  carve((size_t)(N_GRAPHS + 1) * 4);
    unsigned int* g = (unsigned int*)carve((size_t)N_GRAPHS * 256 * 4);
    int*   bsum    = (int*)  carve((size_t)nb * 4);
    int*   boff    = (int*)  carve((size_t)nb * 4);
    (void)ws_size; (void)n_in; (void)out_size;

    hipMemsetAsync(deg, 0, (size_t)N * 4, stream);
    hipMemsetAsync(fill, 0, (size_t)N * 4, stream);
    hipMemsetAsync(g, 0, (size_t)N_GRAPHS * 256 * 4, stream);

    int eb = (E + 255) / 256;

    k_deg<<<eb, 256, 0, stream>>>(dst, E, deg);
    k_dis<<<nb, 256, 0, stream>>>(deg, x, dis, xp, N);
    k_bsum<<<nb, 256, 0, stream>>>(deg, N, bsum);
    k_scan_sums<<<1, 256, 0, stream>>>(bsum, nb, boff);
    k_scan_apply<<<nb, 256, 0, stream>>>(deg, boff, row_ptr, N);
    k_scatter<<<eb, 256, 0, stream>>>(src, dst, E, row_ptr, fill, csr);

    k_agg_scalar<<<nb, 256, 0, stream>>>(xp, dis, row_ptr, csr, t, N);
    k_h1<<<(N * 128 + 255) / 256, 256, 0, stream>>>(t, dis, W1, b1, B1, N);

    k_agg128<<<(N + 7) / 8, 256, 0, stream>>>((const float4*)B1, dis, row_ptr, csr,
                                              (float4*)B2, N);
    k_gemm<128, true><<<dim3((N + 63) / 64, 1), 256, 0, stream>>>(B2, W2, b2, dis, B1, N);

    k_agg128<<<(N + 7) / 8, 256, 0, stream>>>((const float4*)B1, dis, row_ptr, csr,
                                              (float4*)B2, N);
    k_gemm<256, false><<<dim3((N + 63) / 64, 2), 256, 0, stream>>>(B2, W3, b3, nullptr, B3, N);

    k_bounds<<<nb, 256, 0, stream>>>(bat, N, gstart);
    k_gmax<<<dim3(N_GRAPHS, 16), 64, 0, stream>>>((const float4*)B3, gstart, g);
    k_mlp<<<N_GRAPHS, 128, 0, stream>>>((const float*)g, Wf1, bf1, Wf2, bf2, out);
}

// Round 3
// 346.144 us; speedup vs baseline: 2.3789x; 1.1958x over previous
//
#include <hip/hip_runtime.h>
#include <hip/hip_bf16.h>

#define N_GRAPHS 64

// ---------------------------------------------------------------------------
__global__ void k_deg(const int* __restrict__ dst, int E, int* __restrict__ deg) {
    int i = blockIdx.x * blockDim.x + threadIdx.x;
    if (i < E) atomicAdd(&deg[dst[i]], 1);
}

__global__ void k_dis(const int* __restrict__ deg, const float* __restrict__ x,
                      float* __restrict__ dis, float* __restrict__ xp, int N) {
    int i = blockIdx.x * blockDim.x + threadIdx.x;
    if (i < N) {
        float d = rsqrtf((float)(deg[i] + 1));
        dis[i] = d;
        xp[i]  = d * x[i];
    }
}

// ---- hierarchical exclusive scan of deg -> row_ptr[0..N] -------------------
__device__ inline int block_scan_inc(int v, int* wsum) {
    int lane = threadIdx.x & 63, w = threadIdx.x >> 6;
    int iv = v;
#pragma unroll
    for (int o = 1; o < 64; o <<= 1) {
        int t = __shfl_up(iv, o);
        if (lane >= o) iv += t;
    }
    if (lane == 63) wsum[w] = iv;
    __syncthreads();
    int add = 0;
    for (int k = 0; k < w; ++k) add += wsum[k];
    return iv + add;
}

__global__ void k_bsum(const int* __restrict__ deg, int N, int* __restrict__ bsum) {
    int i = blockIdx.x * 256 + threadIdx.x;
    int v = (i < N) ? deg[i] : 0;
#pragma unroll
    for (int o = 1; o < 64; o <<= 1) v += __shfl_xor(v, o);
    __shared__ int ws4[4];
    if ((threadIdx.x & 63) == 0) ws4[threadIdx.x >> 6] = v;
    __syncthreads();
    if (threadIdx.x == 0) bsum[blockIdx.x] = ws4[0] + ws4[1] + ws4[2] + ws4[3];
}

__global__ void k_scan_sums(const int* __restrict__ bsum, int nb, int* __restrict__ boff) {
    __shared__ int wsum[4];
    int tid = threadIdx.x;
    int v = (tid < nb) ? bsum[tid] : 0;
    int inc = block_scan_inc(v, wsum);
    if (tid < nb) boff[tid] = inc - v;   // exclusive
}

__global__ void k_scan_apply(const int* __restrict__ deg, const int* __restrict__ boff,
                             int* __restrict__ row_ptr, int N) {
    __shared__ int wsum[4];
    int b = blockIdx.x, i = b * 256 + threadIdx.x;
    int v = (i < N) ? deg[i] : 0;
    int inc = block_scan_inc(v, wsum) + boff[b];
    if (i < N) {
        row_ptr[i] = inc - v;
        if (i == N - 1) row_ptr[N] = inc;
    }
}

// ---------------------------------------------------------------------------
__global__ void k_scatter(const int* __restrict__ src, const int* __restrict__ dst, int E,
                          const int* __restrict__ row_ptr, int* __restrict__ fill,
                          int* __restrict__ csr_src) {
    int e = blockIdx.x * blockDim.x + threadIdx.x;
    if (e < E) {
        int d = dst[e];
        int pos = row_ptr[d] + atomicAdd(&fill[d], 1);
        csr_src[pos] = src[e];
    }
}

// t[d] = dis[d] * ( sum xp[s] + xp[d] )
__global__ void k_agg_scalar(const float* __restrict__ xp, const float* __restrict__ dis,
                             const int* __restrict__ row_ptr, const int* __restrict__ csr,
                             float* __restrict__ t, int N) {
    int d = blockIdx.x * blockDim.x + threadIdx.x;
    if (d >= N) return;
    float acc = xp[d];
    int e0 = row_ptr[d], e1 = row_ptr[d + 1];
    int e = e0;
    for (; e + 4 <= e1; e += 4) {
        int s0 = csr[e], s1 = csr[e + 1], s2 = csr[e + 2], s3 = csr[e + 3];
        acc += xp[s0] + xp[s1] + xp[s2] + xp[s3];
    }
    for (; e < e1; ++e) acc += xp[csr[e]];
    t[d] = dis[d] * acc;
}

// h1'[i][j] = dis[i] * relu(t[i]*W1[j] + b1[j])
__global__ void k_h1(const float* __restrict__ t, const float* __restrict__ dis,
                     const float* __restrict__ W1, const float* __restrict__ b1,
                     float* __restrict__ h1, int N) {
    __shared__ float w[128], bb[128];
    const int tid = threadIdx.x;
    if (tid < 128) { w[tid] = W1[tid]; bb[tid] = b1[tid]; }
    __syncthreads();
    int idx = blockIdx.x * 256 + tid;
    if (idx < N * 128) {
        int i = idx >> 7, j = idx & 127;
        float v = fmaf(t[i], w[j], bb[j]);
        h1[idx] = fmaxf(v, 0.f) * dis[i];
    }
}

// out[d][:] = dis[d] * ( sum_{s in N(d)} hp[s][:] + hp[d][:] ),  F = 128
__global__ void k_agg128(const float4* __restrict__ hp4, const float* __restrict__ dis,
                         const int* __restrict__ row_ptr, const int* __restrict__ csr,
                         float4* __restrict__ out4, int N) {
    int node = blockIdx.x * 8 + (threadIdx.x >> 5);
    int lane = threadIdx.x & 31;
    if (node >= N) return;
    float4 self = hp4[(size_t)node * 32 + lane];
    float a0 = self.x, a1 = self.y, a2 = self.z, a3 = self.w;
    int e0 = row_ptr[node], e1 = row_ptr[node + 1];
    int e = e0;
    for (; e + 4 <= e1; e += 4) {
        int s0 = csr[e], s1 = csr[e + 1], s2 = csr[e + 2], s3 = csr[e + 3];
        float4 v0 = hp4[(size_t)s0 * 32 + lane];
        float4 v1 = hp4[(size_t)s1 * 32 + lane];
        float4 v2 = hp4[(size_t)s2 * 32 + lane];
        float4 v3 = hp4[(size_t)s3 * 32 + lane];
        a0 += (v0.x + v1.x) + (v2.x + v3.x);
        a1 += (v0.y + v1.y) + (v2.y + v3.y);
        a2 += (v0.z + v1.z) + (v2.z + v3.z);
        a3 += (v0.w + v1.w) + (v2.w + v3.w);
    }
    for (; e < e1; ++e) {
        int s = csr[e];
        float4 v = hp4[(size_t)s * 32 + lane];
        a0 += v.x; a1 += v.y; a2 += v.z; a3 += v.w;
    }
    float d = dis[node];
    out4[(size_t)node * 32 + lane] = make_float4(a0 * d, a1 * d, a2 * d, a3 * d);
}

// GEMM: out[n][jh*128+j] = relu( A[n,:] @ W[:, jh*128+j] + b ) (* dis[n] if SCALE)
// K=128 chunked by 32. Block tile 64 nodes x 128 cols, 26 KiB LDS -> 4 blocks/CU.
// Thread (ng=tid>>4, cg=tid&15): nodes {n0+ng+16m}, cols {cg*4..+3} u {64+cg*4..+3}
// (split-column mapping -> 16B-stride b128 LDS reads, 2-way bank alias = free).
template<int FOUT, bool SCALE>
__global__ __launch_bounds__(256, 4) void k_gemm(const float* __restrict__ A,
                                                 const float* __restrict__ W,
                                                 const float* __restrict__ b,
                                                 const float* __restrict__ dis,
                                                 float* __restrict__ out, int N) {
    __shared__ float Al[64][36];     // 9216 B, node-major, rows 16B-aligned
    __shared__ float Wl[32][132];    // 16896 B, k-major, rows 16B-aligned
    const int tid = threadIdx.x;
    const int n0 = blockIdx.x * 64;
    const int jh = blockIdx.y;
    const int ng = tid >> 4;
    const int cg = tid & 15;

    float acc[4][8] = {};

    for (int kc = 0; kc < 128; kc += 32) {
        // stage A chunk: Al[nn][kk] = A[n0+nn][kc+kk], kk in [0,32)
        for (int idx = tid; idx < 512; idx += 256) {
            int nn = idx >> 3, kq = idx & 7;           // kq fastest: 128B/row segments
            int node = n0 + nn;
            float4 a = (node < N)
                ? reinterpret_cast<const float4*>(A + (size_t)node * 128 + kc)[kq]
                : make_float4(0.f, 0.f, 0.f, 0.f);
            *reinterpret_cast<float4*>(&Al[nn][kq * 4]) = a;
        }
        // stage W chunk: Wl[kk][j] = W[(kc+kk)*FOUT + jh*128 + j]
        for (int idx = tid; idx < 1024; idx += 256) {
            int kk = idx >> 5, jc = idx & 31;          // jc fastest: coalesced
            float4 w = reinterpret_cast<const float4*>(
                W + (size_t)(kc + kk) * FOUT + jh * 128)[jc];
            *reinterpret_cast<float4*>(&Wl[kk][jc * 4]) = w;
        }
        __syncthreads();

#pragma unroll
        for (int k4 = 0; k4 < 8; ++k4) {               // 4 k-steps per iter
            float4 a0 = *reinterpret_cast<const float4*>(&Al[ng     ][k4 * 4]);
            float4 a1 = *reinterpret_cast<const float4*>(&Al[ng + 16][k4 * 4]);
            float4 a2 = *reinterpret_cast<const float4*>(&Al[ng + 32][k4 * 4]);
            float4 a3 = *reinterpret_cast<const float4*>(&Al[ng + 48][k4 * 4]);
            const float am[4][4] = {{a0.x,a0.y,a0.z,a0.w},{a1.x,a1.y,a1.z,a1.w},
                                    {a2.x,a2.y,a2.z,a2.w},{a3.x,a3.y,a3.z,a3.w}};
#pragma unroll
            for (int kk = 0; kk < 4; ++kk) {
                float4 w0 = *reinterpret_cast<const float4*>(&Wl[k4 * 4 + kk][cg * 4]);
                float4 w1 = *reinterpret_cast<const float4*>(&Wl[k4 * 4 + kk][64 + cg * 4]);
                const float wv[8] = {w0.x,w0.y,w0.z,w0.w,w1.x,w1.y,w1.z,w1.w};
#pragma unroll
                for (int m = 0; m < 4; ++m)
#pragma unroll
                    for (int j = 0; j < 8; ++j)
                        acc[m][j] = fmaf(am[m][kk], wv[j], acc[m][j]);
            }
        }
        __syncthreads();
    }

    const float* bb = b + jh * 128;
#pragma unroll
    for (int m = 0; m < 4; ++m) {
        int node = n0 + ng + 16 * m;
        if (node < N) {
            float dsc = SCALE ? dis[node] : 1.f;
            float o[8];
#pragma unroll
            for (int j = 0; j < 4; ++j) {
                o[j]     = fmaxf(acc[m][j]     + bb[cg * 4 + j],      0.f);
                o[j + 4] = fmaxf(acc[m][j + 4] + bb[64 + cg * 4 + j], 0.f);
            }
            if (SCALE) {
#pragma unroll
                for (int j = 0; j < 8; ++j) o[j] *= dsc;
            }
            float* op = out + (size_t)node * FOUT + jh * 128;
            *reinterpret_cast<float4*>(op + cg * 4)      = make_float4(o[0], o[1], o[2], o[3]);
            *reinterpret_cast<float4*>(op + 64 + cg * 4) = make_float4(o[4], o[5], o[6], o[7]);
        }
    }
}

// graph boundary offsets from sorted batch
__global__ void k_bounds(const int* __restrict__ batch, int N, int* __restrict__ gstart) {
    int i = blockIdx.x * blockDim.x + threadIdx.x;
    if (i >= N) return;
    int b = batch[i];
    int prev = (i == 0) ? -1 : batch[i - 1];
    for (int g = prev + 1; g <= b; ++g) gstart[g] = i;
    if (i == N - 1) for (int g = b + 1; g <= N_GRAPHS; ++g) gstart[g] = N;
}

// per-graph max: grid (64 graphs x 16 chunks), 64 threads, float4/lane.
__global__ void k_gmax(const float4* __restrict__ h3, const int* __restrict__ gstart,
                       unsigned int* __restrict__ g) {
    int gid = blockIdx.x;
    int c = blockIdx.y;
    int lane = threadIdx.x;
    int r0 = gstart[gid], r1 = gstart[gid + 1];
    int len = r1 - r0;
    int per = (len + 15) >> 4;
    int s = r0 + c * per;
    int e = min(r1, s + per);
    float4 m = make_float4(0.f, 0.f, 0.f, 0.f);
    for (int i = s; i < e; ++i) {
        float4 v = h3[(size_t)i * 64 + lane];
        m.x = fmaxf(m.x, v.x); m.y = fmaxf(m.y, v.y);
        m.z = fmaxf(m.z, v.z); m.w = fmaxf(m.w, v.w);
    }
    unsigned int* gp = g + gid * 256 + lane * 4;
    atomicMax(gp + 0, __float_as_uint(m.x));
    atomicMax(gp + 1, __float_as_uint(m.y));
    atomicMax(gp + 2, __float_as_uint(m.z));
    atomicMax(gp + 3, __float_as_uint(m.w));
}

// final MLP: out = relu( relu(g@Wf1+bf1) @ Wf2 + bf2 )
__global__ void k_mlp(const float* __restrict__ g, const float* __restrict__ Wf1,
                      const float* __restrict__ bf1, const float* __restrict__ Wf2,
                      const float* __restrict__ bf2, float* __restrict__ out) {
    __shared__ float gr[256];
    __shared__ float g1s[128];
    const int gid = blockIdx.x;
    const int tid = threadIdx.x;
    gr[tid] = g[gid * 256 + tid];
    gr[tid + 128] = g[gid * 256 + 128 + tid];
    __syncthreads();
    float acc = bf1[tid];
    for (int k = 0; k < 256; ++k)
        acc = fmaf(gr[k], Wf1[k * 128 + tid], acc);
    g1s[tid] = fmaxf(acc, 0.f);
    __syncthreads();
    if (tid < 10) {
        float a = bf2[tid];
        for (int k = 0; k < 128; ++k)
            a = fmaf(g1s[k], Wf2[k * 10 + tid], a);
        out[gid * 10 + tid] = fmaxf(a, 0.f);
    }
}

// ---------------------------------------------------------------------------
extern "C" void kernel_launch(void* const* d_in, const int* in_sizes, int n_in,
                              void* d_out, int out_size, void* d_ws, size_t ws_size,
                              hipStream_t stream) {
    const float* x   = (const float*)d_in[0];
    const int*   ei  = (const int*)d_in[1];
    const int*   bat = (const int*)d_in[2];
    const float* W1  = (const float*)d_in[3];
    const float* b1  = (const float*)d_in[4];
    const float* W2  = (const float*)d_in[5];
    const float* b2  = (const float*)d_in[6];
    const float* W3  = (const float*)d_in[7];
    const float* b3  = (const float*)d_in[8];
    const float* Wf1 = (const float*)d_in[9];
    const float* bf1 = (const float*)d_in[10];
    const float* Wf2 = (const float*)d_in[11];
    const float* bf2 = (const float*)d_in[12];
    float* out = (float*)d_out;

    const int N = in_sizes[0];          // 50000
    const int E = in_sizes[1] / 2;      // 800000
    const int* src = ei;
    const int* dst = ei + E;

    char* base = (char*)d_ws;
    size_t off = 0;
    auto carve = [&](size_t bytes) -> char* {
        char* p = base + off;
        off = (off + bytes + 255) & ~(size_t)255;
        return p;
    };
    const int nb = (N + 255) / 256;
    int*   deg     = (int*)  carve((size_t)N * 4);
    int*   fill    = (int*)  carve((size_t)N * 4);
    int*   row_ptr = (int*)  carve((size_t)(N + 1) * 4);
    int*   csr     = (int*)  carve((size_t)E * 4);
    float* dis     = (float*)carve((size_t)N * 4);
    float* xp      = (float*)carve((size_t)N * 4);
    float* t       = (float*)carve((size_t)N * 4);
    float* B1      = (float*)carve((size_t)N * 128 * 4);
    float* B2      = (float*)carve((size_t)N * 128 * 4);
    float* B3      = (float*)carve((size_t)N * 256 * 4);
    int*   gstart  = (int*)  carve((size_t)(N_GRAPHS + 1) * 4);
    unsigned int* g = (unsigned int*)carve((size_t)N_GRAPHS * 256 * 4);
    int*   bsum    = (int*)  carve((size_t)nb * 4);
    int*   boff    = (int*)  carve((size_t)nb * 4);
    (void)ws_size; (void)n_in; (void)out_size;

    hipMemsetAsync(deg, 0, (size_t)N * 4, stream);
    hipMemsetAsync(fill, 0, (size_t)N * 4, stream);
    hipMemsetAsync(g, 0, (size_t)N_GRAPHS * 256 * 4, stream);

    int eb = (E + 255) / 256;

    k_deg<<<eb, 256, 0, stream>>>(dst, E, deg);
    k_dis<<<nb, 256, 0, stream>>>(deg, x, dis, xp, N);
    k_bsum<<<nb, 256, 0, stream>>>(deg, N, bsum);
    k_scan_sums<<<1, 256, 0, stream>>>(bsum, nb, boff);
    k_scan_apply<<<nb, 256, 0, stream>>>(deg, boff, row_ptr, N);
    k_scatter<<<eb, 256, 0, stream>>>(src, dst, E, row_ptr, fill, csr);

    k_agg_scalar<<<nb, 256, 0, stream>>>(xp, dis, row_ptr, csr, t, N);
    k_h1<<<(N * 128 + 255) / 256, 256, 0, stream>>>(t, dis, W1, b1, B1, N);

    k_agg128<<<(N + 7) / 8, 256, 0, stream>>>((const float4*)B1, dis, row_ptr, csr,
                                              (float4*)B2, N);
    k_gemm<128, true><<<dim3((N + 63) / 64, 1), 256, 0, stream>>>(B2, W2, b2, dis, B1, N);

    k_agg128<<<(N + 7) / 8, 256, 0, stream>>>((const float4*)B1, dis, row_ptr, csr,
                                              (float4*)B2, N);
    k_gemm<256, false><<<dim3((N + 63) / 64, 2), 256, 0, stream>>>(B2, W3, b3, nullptr, B3, N);

    k_bounds<<<nb, 256, 0, stream>>>(bat, N, gstart);
    k_gmax<<<dim3(N_GRAPHS, 16), 64, 0, stream>>>((const float4*)B3, gstart, g);
    k_mlp<<<N_GRAPHS, 128, 0, stream>>>((const float*)g, Wf1, bf1, Wf2, bf2, out);
}